// Round 2
// baseline (146.672 us; speedup 1.0000x reference)
//
#include <hip/hip_runtime.h>
#include <hip/hip_bf16.h>

// Problem constants (fixed by the reference setup)
#define H_DIM  128
#define NGRAPH 8192
#define NTOTAL 409600
#define CHUNK  64                    // nodes per K2 iteration
#define NCHUNK (NTOTAL / CHUNK)      // 6400
#define GRID2  512                   // persistent blocks (2 per CU)

typedef __attribute__((ext_vector_type(8))) short s16x8;   // 8 bf16 (4 VGPRs)
typedef __attribute__((ext_vector_type(4))) float f32x4;   // MFMA accumulator

__device__ __forceinline__ unsigned short f2bf(float f) {
    unsigned int u = __float_as_uint(f);
    unsigned int r = u + 0x7fffu + ((u >> 16) & 1u);   // RNE
    return (unsigned short)(r >> 16);
}
__device__ __forceinline__ float bf2f(unsigned short h) {
    return __uint_as_float(((unsigned int)h) << 16);
}

// ---------------- K0: W2 f32 -> bf16 (row-major [h][k]) ----------------
__global__ void k0_w2(const float* __restrict__ W2w, unsigned short* __restrict__ w2bf) {
    int i = blockIdx.x * 256 + threadIdx.x;   // grid covers exactly 128*128
    w2bf[i] = f2bf(W2w[i]);
}

// ---------------- K1: v_n gather + a_g = v_n @ W1^T + (W1_b + W2_b) ----
__global__ __launch_bounds__(128) void k1_ag(
    const float* __restrict__ node_emb,
    const int*   __restrict__ last_idx,
    const float* __restrict__ W1w,
    const float* __restrict__ W1b,
    const float* __restrict__ W2b,
    float* __restrict__ a_g,
    float* __restrict__ v_n)
{
    __shared__ float vn[4][H_DIM];
    const int tid = threadIdx.x;
    const int g0  = blockIdx.x * 4;
    #pragma unroll
    for (int g = 0; g < 4; g++) {
        int li = last_idx[g0 + g];
        float v = node_emb[(size_t)li * H_DIM + tid];
        vn[g][tid] = v;
        v_n[(size_t)(g0 + g) * H_DIM + tid] = v;
    }
    __syncthreads();
    float b = W1b[tid] + W2b[tid];
    float a0 = b, a1 = b, a2 = b, a3 = b;
    const float* wrow = W1w + (size_t)tid * H_DIM;
    #pragma unroll 8
    for (int k = 0; k < H_DIM; k += 4) {
        float4 w = *reinterpret_cast<const float4*>(wrow + k);
        a0 += w.x * vn[0][k] + w.y * vn[0][k+1] + w.z * vn[0][k+2] + w.w * vn[0][k+3];
        a1 += w.x * vn[1][k] + w.y * vn[1][k+1] + w.z * vn[1][k+2] + w.w * vn[1][k+3];
        a2 += w.x * vn[2][k] + w.y * vn[2][k+1] + w.z * vn[2][k+2] + w.w * vn[2][k+3];
        a3 += w.x * vn[3][k] + w.y * vn[3][k+1] + w.z * vn[3][k+2] + w.w * vn[3][k+3];
    }
    a_g[(size_t)(g0 + 0) * H_DIM + tid] = a0;
    a_g[(size_t)(g0 + 1) * H_DIM + tid] = a1;
    a_g[(size_t)(g0 + 2) * H_DIM + tid] = a2;
    a_g[(size_t)(g0 + 3) * H_DIM + tid] = a3;
}

// ---------------- K2: persistent fused kernel --------------------------
// 512 blocks x 256 threads; each block grid-strides over chunks with W2
// resident in LDS and the node stage software-pipelined in registers.
__global__ __launch_bounds__(256, 2) void k2_main(
    const float* __restrict__ node_emb,
    const float* __restrict__ num_count,
    const int*   __restrict__ seg_ids,
    const float* __restrict__ a_g,
    const unsigned short* __restrict__ w2bf,
    const float* __restrict__ q_w,
    const float* __restrict__ q_b,
    float* __restrict__ s_g)
{
    __shared__ __align__(16) char w2s[H_DIM * 256];      // 32 KB, swizzled, resident
    __shared__ __align__(16) char ndA[2][CHUNK * 256];   // 2 x 16 KB, swizzled
    __shared__ int   segLds[2][CHUNK];
    __shared__ float alphaLds[CHUNK];
    __shared__ float coefLds[CHUNK];

    const int tid  = threadIdx.x;
    const int lane = tid & 63;
    const int wid  = tid >> 6;
    const int wm = wid >> 1;     // m offset wm*32
    const int wn = wid & 1;      // n offset wn*64
    const int l16 = lane & 15, lq = lane >> 4;

    // --- W2 bf16 -> LDS once per block, XOR swizzled ---
    {
        const uint4* wsrc = reinterpret_cast<const uint4*>(w2bf);
        #pragma unroll
        for (int i = 0; i < 8; i++) {
            int c = i * 256 + tid;
            uint4 v = wsrc[c];
            int byte = c << 4;
            int row  = byte >> 8;
            *reinterpret_cast<uint4*>(w2s + (byte ^ ((row & 7) << 4))) = v;
        }
    }
    if (tid < CHUNK) alphaLds[tid] = 0.f;

    float qv[4];
    #pragma unroll
    for (int nt = 0; nt < 4; nt++) qv[nt] = q_w[wn * 64 + nt * 16 + l16];
    const float qb0 = q_b[0];

    // --- preload first chunk into registers ---
    float4 r[8];
    int   segNext = 0;
    float ncNext  = 0.f;
    {
        const float4* src4 = reinterpret_cast<const float4*>(
            node_emb + (size_t)blockIdx.x * CHUNK * H_DIM);
        #pragma unroll
        for (int i = 0; i < 8; i++) r[i] = src4[i * 256 + tid];
        if (tid < CHUNK) {
            segNext = seg_ids[blockIdx.x * CHUNK + tid];
            ncNext  = num_count[blockIdx.x * CHUNK + tid];
        }
    }

    int it = 0;
    for (int c = blockIdx.x; c < NCHUNK; c += GRID2, it ^= 1) {
        char* nd = ndA[it];

        // --- stage current chunk regs -> bf16 LDS (cvt_pk), swizzled ---
        #pragma unroll
        for (int i = 0; i < 8; i++) {
            int f4   = i * 256 + tid;
            int row  = f4 >> 5;
            int byte = (row << 8) | ((f4 & 31) << 3);
            byte ^= (row & 7) << 4;
            unsigned int p0, p1;
            asm("v_cvt_pk_bf16_f32 %0, %1, %2" : "=v"(p0) : "v"(r[i].x), "v"(r[i].y));
            asm("v_cvt_pk_bf16_f32 %0, %1, %2" : "=v"(p1) : "v"(r[i].z), "v"(r[i].w));
            uint2 pk; pk.x = p0; pk.y = p1;
            *reinterpret_cast<uint2*>(nd + byte) = pk;
        }
        const float ncCur = ncNext;
        if (tid < CHUNK) segLds[it][tid] = segNext;

        // --- issue next chunk's global loads (overlap with compute) ---
        int cn = c + GRID2;
        if (cn < NCHUNK) {
            const float4* src4 = reinterpret_cast<const float4*>(
                node_emb + (size_t)cn * CHUNK * H_DIM);
            #pragma unroll
            for (int i = 0; i < 8; i++) r[i] = src4[i * 256 + tid];
            if (tid < CHUNK) {
                segNext = seg_ids[cn * CHUNK + tid];
                ncNext  = num_count[cn * CHUNK + tid];
            }
        }
        __syncthreads();   // B1: stage visible

        // --- a_g prefetch (before MFMA so L2 latency hides), 4-run dedup ---
        float agv[2][4][4];   // [mt][r][nt]
        #pragma unroll
        for (int mt = 0; mt < 2; mt++) {
            int mb = wm * 32 + mt * 16 + lq * 4;
            int s0 = segLds[it][mb];
            int s3 = segLds[it][mb + 3];
            const float* a0 = a_g + (size_t)s0 * H_DIM + wn * 64 + l16;
            #pragma unroll
            for (int nt = 0; nt < 4; nt++) agv[mt][0][nt] = a0[nt * 16];
            if (s0 == s3) {
                #pragma unroll
                for (int rr = 1; rr < 4; rr++)
                    #pragma unroll
                    for (int nt = 0; nt < 4; nt++) agv[mt][rr][nt] = agv[mt][0][nt];
            } else {
                #pragma unroll
                for (int rr = 1; rr < 4; rr++) {
                    const float* ar = a_g + (size_t)segLds[it][mb + rr] * H_DIM + wn * 64 + l16;
                    #pragma unroll
                    for (int nt = 0; nt < 4; nt++) agv[mt][rr][nt] = ar[nt * 16];
                }
            }
        }

        // --- MFMA: z[m][h] = sum_k node[m][k] * W2[h][k] ---
        f32x4 acc[2][4];
        #pragma unroll
        for (int mt = 0; mt < 2; mt++)
            #pragma unroll
            for (int nt = 0; nt < 4; nt++)
                acc[mt][nt] = f32x4{0.f, 0.f, 0.f, 0.f};
        #pragma unroll
        for (int ks = 0; ks < 4; ks++) {
            s16x8 af[2];
            #pragma unroll
            for (int mt = 0; mt < 2; mt++) {
                int row  = wm * 32 + mt * 16 + l16;
                int byte = (row << 8) | ((lq * 8 + ks * 32) << 1);
                byte ^= (row & 7) << 4;
                af[mt] = *reinterpret_cast<const s16x8*>(nd + byte);
            }
            s16x8 bfr[4];
            #pragma unroll
            for (int nt = 0; nt < 4; nt++) {
                int row  = wn * 64 + nt * 16 + l16;
                int byte = (row << 8) | ((lq * 8 + ks * 32) << 1);
                byte ^= (row & 7) << 4;
                bfr[nt] = *reinterpret_cast<const s16x8*>(w2s + byte);
            }
            #pragma unroll
            for (int mt = 0; mt < 2; mt++)
                #pragma unroll
                for (int nt = 0; nt < 4; nt++)
                    acc[mt][nt] = __builtin_amdgcn_mfma_f32_16x16x32_bf16(
                                      af[mt], bfr[nt], acc[mt][nt], 0, 0, 0);
        }

        // --- alpha: sum_h sigmoid(z + a_g) * q_w[h], 16-lane shfl reduce ---
        #pragma unroll
        for (int mt = 0; mt < 2; mt++) {
            #pragma unroll
            for (int rr = 0; rr < 4; rr++) {
                int m = wm * 32 + mt * 16 + lq * 4 + rr;   // D row = (lane>>4)*4 + rr
                float p = 0.f;
                #pragma unroll
                for (int nt = 0; nt < 4; nt++) {
                    float z = acc[mt][nt][rr] + agv[mt][rr][nt];
                    float g = 1.f / (1.f + __expf(-z));
                    p += g * qv[nt];
                }
                p += __shfl_xor(p, 1, 64);
                p += __shfl_xor(p, 2, 64);
                p += __shfl_xor(p, 4, 64);
                p += __shfl_xor(p, 8, 64);
                if (l16 == 0) atomicAdd(&alphaLds[m], p);
            }
        }
        __syncthreads();   // B2: alpha complete
        if (tid < CHUNK) {
            coefLds[tid]  = ncCur * (alphaLds[tid] + qb0);
            alphaLds[tid] = 0.f;   // reset for next iteration
        }
        __syncthreads();   // B3: coef visible

        // --- segment-sum: s_g[seg][h] += coef[m]*node[m][h], 2 h per thread ---
        {
            int h2 = tid & 63;       // h pair index: h = 2*h2
            int mq = tid >> 6;       // 16-node quarter
            int m0 = mq * 16;
            float a0s = 0.f, a1s = 0.f;
            int cur = segLds[it][m0];
            #pragma unroll 4
            for (int m = m0; m < m0 + 16; m++) {
                int s = segLds[it][m];
                if (s != cur) {
                    atomicAdd(s_g + (size_t)cur * H_DIM + 2 * h2,     a0s);
                    atomicAdd(s_g + (size_t)cur * H_DIM + 2 * h2 + 1, a1s);
                    a0s = 0.f; a1s = 0.f; cur = s;
                }
                int byte = (m << 8) | (h2 << 2);
                byte ^= (m & 7) << 4;
                unsigned int u = *reinterpret_cast<const unsigned int*>(nd + byte);
                float c0 = __uint_as_float(u << 16);
                float c1 = __uint_as_float(u & 0xffff0000u);
                float cf = coefLds[m];
                a0s += cf * c0;
                a1s += cf * c1;
            }
            atomicAdd(s_g + (size_t)cur * H_DIM + 2 * h2,     a0s);
            atomicAdd(s_g + (size_t)cur * H_DIM + 2 * h2 + 1, a1s);
        }
        // next iteration writes ndA[it^1]/segLds[it^1] — disjoint from the
        // buffers still being read here; coefLds/alphaLds rewrites are
        // barrier-separated (B1/B2 of the next iteration).
    }
}

// ---------------- K3: s_h = [v_n | s_g] @ W3^T + W3_b ------------------
__global__ __launch_bounds__(128) void k3_out(
    const float* __restrict__ v_n,
    const float* __restrict__ s_g,
    const float* __restrict__ W3w,
    const float* __restrict__ W3b,
    float* __restrict__ out)
{
    __shared__ float cat[8][2 * H_DIM];
    const int tid = threadIdx.x;
    const int g0  = blockIdx.x * 8;
    #pragma unroll
    for (int g = 0; g < 8; g++) {
        cat[g][tid]         = v_n[(size_t)(g0 + g) * H_DIM + tid];
        cat[g][H_DIM + tid] = s_g[(size_t)(g0 + g) * H_DIM + tid];
    }
    __syncthreads();
    float acc[8];
    float b = W3b[tid];
    #pragma unroll
    for (int g = 0; g < 8; g++) acc[g] = b;
    const float* wrow = W3w + (size_t)tid * (2 * H_DIM);
    for (int k = 0; k < 2 * H_DIM; k += 4) {
        float4 w = *reinterpret_cast<const float4*>(wrow + k);
        #pragma unroll
        for (int g = 0; g < 8; g++)
            acc[g] += w.x * cat[g][k] + w.y * cat[g][k+1]
                    + w.z * cat[g][k+2] + w.w * cat[g][k+3];
    }
    #pragma unroll
    for (int g = 0; g < 8; g++)
        out[(size_t)(g0 + g) * H_DIM + tid] = acc[g];
}

extern "C" void kernel_launch(void* const* d_in, const int* in_sizes, int n_in,
                              void* d_out, int out_size, void* d_ws, size_t ws_size,
                              hipStream_t stream) {
    const float* node_emb  = (const float*)d_in[0];
    const float* num_count = (const float*)d_in[1];
    // d_in[2] sections: unused
    const int*   seg_ids   = (const int*)d_in[3];
    const int*   last_idx  = (const int*)d_in[4];
    // d_in[5..8] unused
    const float* W1w = (const float*)d_in[9];
    const float* W1b = (const float*)d_in[10];
    const float* W2w = (const float*)d_in[11];
    const float* W2b = (const float*)d_in[12];
    const float* qw  = (const float*)d_in[13];
    const float* qb  = (const float*)d_in[14];
    const float* W3w = (const float*)d_in[15];
    const float* W3b = (const float*)d_in[16];
    float* out = (float*)d_out;

    char* ws = (char*)d_ws;
    float* a_g = (float*)(ws);                          // 4 MB
    float* v_n = (float*)(ws + (4u  << 20));            // 4 MB
    float* s_g = (float*)(ws + (8u  << 20));            // 4 MB
    unsigned short* w2bf = (unsigned short*)(ws + (12u << 20));  // 32 KB

    hipMemsetAsync(s_g, 0, (size_t)NGRAPH * H_DIM * sizeof(float), stream);
    k0_w2 <<<64,   256, 0, stream>>>(W2w, w2bf);
    k1_ag <<<NGRAPH / 4, 128, 0, stream>>>(node_emb, last_idx, W1w, W1b, W2b, a_g, v_n);
    k2_main<<<GRID2, 256, 0, stream>>>(node_emb, num_count, seg_ids, a_g,
                                       w2bf, qw, qb, s_g);
    k3_out<<<NGRAPH / 8, 128, 0, stream>>>(v_n, s_g, W3w, W3b, out);
}